// Round 4
// baseline (470.246 us; speedup 1.0000x reference)
//
#include <hip/hip_runtime.h>

// TargetOpinionPairRepresentation on MI355X.
// Output row r = b*4096 + p, p = t*64 + o:
//   out[r] = concat( spans[b, target_indices[b,t]],   // 768 f32
//                    spans[b, opinion_indices[b,o]],  // 768 f32
//                    dist_emb[bucket(width)] )        // 128 f32
// width = min(|b_end - c_start|, |a_start - d_end|) from span_indices.
// bucket = searchsorted(BINS, width, right) - 1 = sum(width >= BINS[i]) - 1.

#define B_DIM 16
#define S_DIM 512
#define D_DIM 768
#define E_DIM 128
#define T_DIM 64
#define O_DIM 64
#define ROW_FLOATS (2 * D_DIM + E_DIM)   // 1664
#define ROW_F4 (ROW_FLOATS / 4)          // 416
#define D_F4 (D_DIM / 4)                 // 192

// Native clang vector type: __builtin_nontemporal_store requires a
// vector-of-scalar type, not HIP's float4 class.
typedef float f32x4 __attribute__((ext_vector_type(4)));

__global__ __launch_bounds__(256) void pair_rep_kernel(
    const float* __restrict__ spans,           // [B,S,D]
    const float* __restrict__ dist_emb,        // [14,E]
    const int*   __restrict__ span_indices,    // [S,2]
    const int*   __restrict__ target_indices,  // [B,T]
    const int*   __restrict__ opinion_indices, // [B,O]
    float*       __restrict__ out)             // [B,P,1664]
{
    const int row = blockIdx.x;          // 0 .. B*P-1
    const int b   = row >> 12;           // / 4096
    const int p   = row & 4095;
    const int t   = p >> 6;              // / 64
    const int o   = p & 63;

    const int ti = target_indices[b * T_DIM + t];
    const int oi = opinion_indices[b * O_DIM + o];

    const int a_ = span_indices[2 * ti];
    const int b_ = span_indices[2 * ti + 1];
    const int c_ = span_indices[2 * oi];
    const int d_ = span_indices[2 * oi + 1];
    const int w1 = abs(b_ - c_);
    const int w2 = abs(a_ - d_);
    const int width = min(w1, w2);

    // bucket = (# bins <= width) - 1, bins fixed
    const int bins[14] = {0, 1, 2, 3, 4, 5, 7, 8, 15, 16, 31, 32, 63, 64};
    int bucket = -1;
#pragma unroll
    for (int i = 0; i < 14; ++i) bucket += (width >= bins[i]) ? 1 : 0;

    const f32x4* st = (const f32x4*)(spans + ((size_t)b * S_DIM + ti) * D_DIM);
    const f32x4* so = (const f32x4*)(spans + ((size_t)b * S_DIM + oi) * D_DIM);
    const f32x4* de = (const f32x4*)(dist_emb + (size_t)bucket * E_DIM);
    f32x4* dst = (f32x4*)(out + (size_t)row * ROW_FLOATS);

    for (int c4 = threadIdx.x; c4 < ROW_F4; c4 += 256) {
        f32x4 v;
        if (c4 < D_F4) {
            v = st[c4];
        } else if (c4 < 2 * D_F4) {
            v = so[c4 - D_F4];
        } else {
            v = de[c4 - 2 * D_F4];
        }
        // Streaming 436 MB with zero reuse: bypass cache so span rows stay hot.
        __builtin_nontemporal_store(v, &dst[c4]);
    }
}

extern "C" void kernel_launch(void* const* d_in, const int* in_sizes, int n_in,
                              void* d_out, int out_size, void* d_ws, size_t ws_size,
                              hipStream_t stream) {
    const float* spans           = (const float*)d_in[0];
    const float* dist_emb        = (const float*)d_in[1];
    const int*   span_indices    = (const int*)d_in[2];
    const int*   target_indices  = (const int*)d_in[3];
    const int*   opinion_indices = (const int*)d_in[4];
    float* out = (float*)d_out;

    const int n_rows = B_DIM * T_DIM * O_DIM;  // 65536
    pair_rep_kernel<<<n_rows, 256, 0, stream>>>(
        spans, dist_emb, span_indices, target_indices, opinion_indices, out);
}